// Round 6
// baseline (252.912 us; speedup 1.0000x reference)
//
#include <hip/hip_runtime.h>
#include <hip/hip_bf16.h>
#include <math.h>

#define D_MODEL 1024
#define NUM_HEADS 16
#define DK 64
#define BATCH 2
#define SEQ 2048
#define NROWS (BATCH * SEQ) /* 4096 */

typedef __bf16 bf16x8 __attribute__((ext_vector_type(8)));
typedef __bf16 bf16x4 __attribute__((ext_vector_type(4)));
typedef float f32x4 __attribute__((ext_vector_type(4)));

// async global->LDS, 16 B per lane; LDS dest = wave-uniform base + lane*16
#define GLOAD_LDS16(g, l)                                          \
  __builtin_amdgcn_global_load_lds(                                \
      (const __attribute__((address_space(1))) void*)(g),          \
      (__attribute__((address_space(3))) void*)(l), 16, 0, 0)

// LDS-only wait + compiler reorder fence (NO vmcnt drain — keeps global
// prefetch loads in flight)
#define LDS_FENCE() asm volatile("s_waitcnt lgkmcnt(0)" ::: "memory")

// rotate 4 (even,odd) pairs of a bf16x8 by RoPE angles; p0 = first pair idx.
// scale applied after rotation (1.0 for K; 0.125*log2e for Q).
__device__ inline bf16x8 rope8(bf16x8 v, float pos, int p0, float scale) {
#pragma unroll
  for (int j = 0; j < 4; ++j) {
    float ang = pos * exp2f(-(float)(p0 + j) * 0.41524101186091903f);
    float cs = cosf(ang), sn = sinf(ang);
    float e = (float)v[2 * j], o = (float)v[2 * j + 1];
    v[2 * j]     = (__bf16)((e * cs - o * sn) * scale);
    v[2 * j + 1] = (__bf16)((e * sn + o * cs) * scale);
  }
  return v;
}

// ---------------- fused fp32 -> bf16 conversion ----------------------------
// wq/wk/wv packed contiguous into wqkvb (3072 x 1024); wo separate.
__global__ void cvt_all_kernel(const float* __restrict__ x,
                               const float* __restrict__ wq,
                               const float* __restrict__ wk,
                               const float* __restrict__ wv,
                               const float* __restrict__ wo,
                               __hip_bfloat16* __restrict__ xb,
                               __hip_bfloat16* __restrict__ wqkvb,
                               __hip_bfloat16* __restrict__ wob) {
  int t = blockIdx.x * 256 + threadIdx.x;  // 2,097,152 float4 units total
  const float* src;
  __hip_bfloat16* dst;
  int off;
  if (t < 1048576) {
    src = x; dst = xb; off = t;
  } else {
    int u = t - 1048576;
    int w = u >> 18;  // 262144 float4 per weight
    off = u & 262143;
    src = (w == 0) ? wq : (w == 1) ? wk : (w == 2) ? wv : wo;
    dst = (w < 3) ? (wqkvb + (size_t)w * 1048576) : wob;
  }
  float4 v = reinterpret_cast<const float4*>(src)[off];
  union { __hip_bfloat16 h[4]; uint2 u; } tmp;
  tmp.h[0] = __float2bfloat16(v.x);
  tmp.h[1] = __float2bfloat16(v.y);
  tmp.h[2] = __float2bfloat16(v.z);
  tmp.h[3] = __float2bfloat16(v.w);
  reinterpret_cast<uint2*>(dst)[off] = tmp.u;
}

// ---------------- QKV GEMM (m97 + 1-barrier dbuf) --------------------------
// C[m,n] = sum_k A[m,k] * W[n,k]; W packed (3072 rows) -> Q/K/V by n>>10.
__global__ __launch_bounds__(256)
void gemm_qkv_kernel(const __hip_bfloat16* __restrict__ A,
                     const __hip_bfloat16* __restrict__ W,
                     __hip_bfloat16* __restrict__ O0,
                     __hip_bfloat16* __restrict__ O1,
                     __hip_bfloat16* __restrict__ O2) {
  __shared__ __hip_bfloat16 sA[2][128 * 32];
  __shared__ __hip_bfloat16 sB[2][128 * 32];
  const int tid = threadIdx.x;
  const int wave = tid >> 6, lane = tid & 63, quad = lane >> 4, l16 = lane & 15;
  const int wm = (wave >> 1) * 64, wn = (wave & 1) * 64;
  const int bm = blockIdx.x * 128;
  const int bnG = blockIdx.y * 128;  // row base into packed W
  int which = blockIdx.y >> 3;
  __hip_bfloat16* O = (which == 0) ? O0 : (which == 1) ? O1 : O2;
  const int ocol = bnG & 1023;
  const int srow = lane >> 2, scol = (lane & 3) * 8;

#pragma unroll
  for (int c = 0; c < 2; ++c) {
    int ch = wave + c * 4;
    GLOAD_LDS16(&A[(size_t)(bm + ch * 16 + srow) * D_MODEL + scol], &sA[0][ch * 512]);
    GLOAD_LDS16(&W[(size_t)(bnG + ch * 16 + srow) * D_MODEL + scol], &sB[0][ch * 512]);
  }

  f32x4 acc[4][4] = {};
  for (int it = 0; it < 32; ++it) {
    __syncthreads();
    if (it + 1 < 32) {
      const int k0 = (it + 1) * 32, nb = (it + 1) & 1;
#pragma unroll
      for (int c = 0; c < 2; ++c) {
        int ch = wave + c * 4;
        GLOAD_LDS16(&A[(size_t)(bm + ch * 16 + srow) * D_MODEL + k0 + scol],
                    &sA[nb][ch * 512]);
        GLOAD_LDS16(&W[(size_t)(bnG + ch * 16 + srow) * D_MODEL + k0 + scol],
                    &sB[nb][ch * 512]);
      }
    }
    const int cb = it & 1;
    bf16x8 af[4], bfb[4];
#pragma unroll
    for (int i = 0; i < 4; ++i)
      af[i] = *reinterpret_cast<bf16x8*>(&sA[cb][(wm + i * 16 + l16) * 32 + quad * 8]);
#pragma unroll
    for (int j = 0; j < 4; ++j)
      bfb[j] = *reinterpret_cast<bf16x8*>(&sB[cb][(wn + j * 16 + l16) * 32 + quad * 8]);
#pragma unroll
    for (int i = 0; i < 4; ++i)
#pragma unroll
      for (int j = 0; j < 4; ++j)
        acc[i][j] = __builtin_amdgcn_mfma_f32_16x16x32_bf16(af[i], bfb[j], acc[i][j], 0, 0, 0);
  }

#pragma unroll
  for (int i = 0; i < 4; ++i)
#pragma unroll
    for (int j = 0; j < 4; ++j)
#pragma unroll
      for (int r = 0; r < 4; ++r) {
        int row = bm + wm + i * 16 + quad * 4 + r;
        int col = ocol + wn + j * 16 + l16;
        O[(size_t)row * D_MODEL + col] = __float2bfloat16(acc[i][j][r]);
      }
}

// ---------------- out-proj GEMM, 64x128 tile (512 blocks -> 2/CU) ----------
__global__ __launch_bounds__(256)
void gemm_out_kernel(const __hip_bfloat16* __restrict__ A,
                     const __hip_bfloat16* __restrict__ W,
                     float* __restrict__ O) {
  __shared__ __hip_bfloat16 sA[2][64 * 32];
  __shared__ __hip_bfloat16 sB[2][128 * 32];
  const int tid = threadIdx.x;
  const int wave = tid >> 6, lane = tid & 63, quad = lane >> 4, l16 = lane & 15;
  const int mh = (wave >> 1) * 32, nh = (wave & 1) * 64;
  const int bm = blockIdx.x * 64, bn = blockIdx.y * 128;
  const int srow = lane >> 2, scol = (lane & 3) * 8;

  GLOAD_LDS16(&A[(size_t)(bm + wave * 16 + srow) * D_MODEL + scol], &sA[0][wave * 512]);
#pragma unroll
  for (int c = 0; c < 2; ++c) {
    int ch = wave + c * 4;
    GLOAD_LDS16(&W[(size_t)(bn + ch * 16 + srow) * D_MODEL + scol], &sB[0][ch * 512]);
  }

  f32x4 acc[2][4] = {};
  for (int it = 0; it < 32; ++it) {
    __syncthreads();
    if (it + 1 < 32) {
      const int k0 = (it + 1) * 32, nb = (it + 1) & 1;
      GLOAD_LDS16(&A[(size_t)(bm + wave * 16 + srow) * D_MODEL + k0 + scol],
                  &sA[nb][wave * 512]);
#pragma unroll
      for (int c = 0; c < 2; ++c) {
        int ch = wave + c * 4;
        GLOAD_LDS16(&W[(size_t)(bn + ch * 16 + srow) * D_MODEL + k0 + scol],
                    &sB[nb][ch * 512]);
      }
    }
    const int cb = it & 1;
    bf16x8 af[2], bfb[4];
#pragma unroll
    for (int i = 0; i < 2; ++i)
      af[i] = *reinterpret_cast<bf16x8*>(&sA[cb][(mh + i * 16 + l16) * 32 + quad * 8]);
#pragma unroll
    for (int j = 0; j < 4; ++j)
      bfb[j] = *reinterpret_cast<bf16x8*>(&sB[cb][(nh + j * 16 + l16) * 32 + quad * 8]);
#pragma unroll
    for (int i = 0; i < 2; ++i)
#pragma unroll
      for (int j = 0; j < 4; ++j)
        acc[i][j] = __builtin_amdgcn_mfma_f32_16x16x32_bf16(af[i], bfb[j], acc[i][j], 0, 0, 0);
  }

#pragma unroll
  for (int i = 0; i < 2; ++i)
#pragma unroll
    for (int j = 0; j < 4; ++j)
#pragma unroll
      for (int r = 0; r < 4; ++r) {
        int row = bm + mh + i * 16 + quad * 4 + r;
        int col = bn + nh + j * 16 + l16;
        O[(size_t)row * D_MODEL + col] = acc[i][j][r];
      }
}

// ---------------- Flash attention (causal) + fused RoPE --------------------
// 256 thd = 4 waves; 512 BALANCED blocks: block = (pair pi, half, b, h).
// q-groups qlo=pi and qhi=15-pi share one kv stream; wave w owns subtile
// jL = half*4+w of qlo-group and jU = 7-jL of qhi-group -> constant
// 2qlo+2qhi+3 = 33 tile-visits per wave, zero tail. S^T orientation,
// XOR-swizzled sPt, no max-subtraction, dbuf staging w/ register prefetch.
// RoPE applied in-kernel: Q pairs in-lane at frag load; K pairs in-lane at
// staging commit (same fp32 math as the old rope kernel).
__global__ __launch_bounds__(256)
void attn_kernel(const __hip_bfloat16* __restrict__ Q,
                 const __hip_bfloat16* __restrict__ K,
                 const __hip_bfloat16* __restrict__ V,
                 const int* __restrict__ tpos,
                 __hip_bfloat16* __restrict__ Ao) {
  constexpr float QS = 0.18033688011112042f;  // 0.125 * log2(e)
  constexpr int LS = 66;  // sK/sVt stride (33 dwords, odd -> bank spread)
  __shared__ __hip_bfloat16 sK[2][64 * LS];
  __shared__ __hip_bfloat16 sVt[2][64 * LS];  // sVt[d][kv]
  __shared__ __hip_bfloat16 sPt[4][16 * 64];  // per-wave, XOR-swizzled
  const int tid = threadIdx.x;
  const int wave = tid >> 6, lane = tid & 63, quad = lane >> 4, l16 = lane & 15;
  const int idx = blockIdx.x;            // 512 blocks, all equal work
  const int bh = idx & 31;
  const int half = (idx >> 5) & 1;
  const int pi = idx >> 6;               // 0..7
  const int qlo = pi, qhi = 15 - pi;
  const int h = bh & 15, b = bh >> 4;
  const int ho = h * DK;
  const size_t rowbase = (size_t)b * SEQ;
  const int jL = half * 4 + wave, jU = 7 - jL;
  const int sbs[2] = {qlo * 128 + jL * 16, qhi * 128 + jU * 16};  // sbs[1]>sbs[0]
  // stream length: block's largest subtile is wave 0's jU
  const int nt = ((qhi * 128 + (7 - half * 4) * 16 + 15) >> 6) + 1;
  const __hip_bfloat16* Kbase = K + rowbase * D_MODEL + ho;
  const unsigned short* Vu =
      reinterpret_cast<const unsigned short*>(V + rowbase * D_MODEL + ho);

  // Q fragments (B-operand; lane l16 = q-row) + fused RoPE (pairs in-lane)
  bf16x8 aq[2][2];
#pragma unroll
  for (int s = 0; s < 2; ++s) {
    float posq = (float)tpos[rowbase + sbs[s] + l16];
#pragma unroll
    for (int kk = 0; kk < 2; ++kk) {
      bf16x8 v = *reinterpret_cast<const bf16x8*>(
          &Q[(rowbase + sbs[s] + l16) * D_MODEL + ho + kk * 32 + quad * 8]);
      aq[s][kk] = rope8(v, posq, kk * 16 + quad * 4, QS);
    }
  }

  f32x4 o_acc[2][4] = {};
  float l_run[2] = {0.f, 0.f};

  // staging maps: K: row = tid>>2, two b128 chunks at (tid&3)*16
  const int krow = tid >> 2, kc = (tid & 3) * 16;
  const int kp0a = kc >> 1, kp0b = (kc + 8) >> 1;  // pair indices for rope
  const int vd = lane;  // V^T: d = lane

  // prologue: stage tile 0 into buffer 0 (K gets rope'd)
  {
    float posk = (float)tpos[rowbase + krow];
    bf16x8 k0 = *reinterpret_cast<const bf16x8*>(&Kbase[(size_t)krow * D_MODEL + kc]);
    bf16x8 k1 = *reinterpret_cast<const bf16x8*>(&Kbase[(size_t)krow * D_MODEL + kc + 8]);
    *reinterpret_cast<bf16x8*>(&sK[0][krow * LS + kc]) = rope8(k0, posk, kp0a, 1.0f);
    *reinterpret_cast<bf16x8*>(&sK[0][krow * LS + kc + 8]) = rope8(k1, posk, kp0b, 1.0f);
#pragma unroll
    for (int c = 0; c < 8; ++c) {
      int u = c * 256 + tid;  // 2048 units = 64 d x 32 kv-pairs
      int d = u & 63, kvp = u >> 6;
      unsigned lo = Vu[(size_t)(2 * kvp) * D_MODEL + d];
      unsigned hi = Vu[(size_t)(2 * kvp + 1) * D_MODEL + d];
      *reinterpret_cast<unsigned*>(&sVt[0][d * LS + 2 * kvp]) = lo | (hi << 16);
    }
  }

  for (int t = 0; t < nt; ++t) {
    __syncthreads();  // staging for tile t visible
    const int buf = t & 1;
    const bool hn = (t + 1) < nt;
    bf16x8 kn0, kn1;
    int posn = 0;
    unsigned vw[8];
    if (hn) {  // register prefetch of next tile (latency overlapped)
      const int kvn = (t + 1) * 64;
      posn = tpos[rowbase + kvn + krow];
      kn0 = *reinterpret_cast<const bf16x8*>(
          &Kbase[(size_t)(kvn + krow) * D_MODEL + kc]);
      kn1 = *reinterpret_cast<const bf16x8*>(
          &Kbase[(size_t)(kvn + krow) * D_MODEL + kc + 8]);
#pragma unroll
      for (int c = 0; c < 8; ++c) {
        int u = c * 256 + tid;
        int d = u & 63, kvp = u >> 6;
        unsigned lo = Vu[(size_t)(kvn + 2 * kvp) * D_MODEL + d];
        unsigned hi = Vu[(size_t)(kvn + 2 * kvp + 1) * D_MODEL + d];
        vw[c] = lo | (hi << 16);
      }
    }

    const int kv0 = t * 64;
    if (kv0 <= sbs[1] + 15) {
      // q-independent fragments: load ONCE, reuse for both subtiles
      bf16x8 ak[2][4], bv[2][4];
#pragma unroll
      for (int kk = 0; kk < 2; ++kk)
#pragma unroll
        for (int j = 0; j < 4; ++j) {
          ak[kk][j] = *reinterpret_cast<bf16x8*>(
              &sK[buf][(j * 16 + l16) * LS + kk * 32 + quad * 8]);
          bv[kk][j] = *reinterpret_cast<bf16x8*>(
              &sVt[buf][(j * 16 + l16) * LS + kk * 32 + quad * 8]);
        }

#pragma unroll
      for (int s = 0; s < 2; ++s) {
        const int sb = sbs[s];
        if (kv0 > sb + 15) continue;
        // S^T = K Q^T : lane holds S[q=sb+l16][kv0 + 16j + 4quad + r]
        f32x4 sv[4] = {};
#pragma unroll
        for (int kk = 0; kk < 2; ++kk)
#pragma unroll
          for (int j = 0; j < 4; ++j)
            sv[j] = __builtin_amdgcn_mfma_f32_16x16x32_bf16(ak[kk][j], aq[s][kk],
                                                            sv[j], 0, 0, 0);
        // Causal mask (diagonal-crossing tiles only)
        if (kv0 + 63 > sb) {
#pragma unroll
          for (int j = 0; j < 4; ++j)
#pragma unroll
            for (int r = 0; r < 4; ++r)
              if (kv0 + j * 16 + quad * 4 + r > sb + l16) sv[j][r] = -INFINITY;
        }
        // exp2; in-lane row-sum; write P rows (q=l16) XOR-swizzled, b64
        float ls = 0.f;
#pragma unroll
        for (int j = 0; j < 4; ++j) {
          bf16x4 pk;
#pragma unroll
          for (int r = 0; r < 4; ++r) {
            float p = __builtin_amdgcn_exp2f(sv[j][r]);
            ls += p;
            pk[r] = (__bf16)p;
          }
          int wgr = (2 * j + (quad >> 1)) ^ (l16 & 7);  // 4-dword granule
          *reinterpret_cast<bf16x4*>(
              &sPt[wave][l16 * 64 + wgr * 8 + (quad & 1) * 4]) = pk;
        }
        l_run[s] += ls;
        LDS_FENCE();  // order sPt write->read (same wave); vmcnt untouched
        // O += P V
#pragma unroll
        for (int kk = 0; kk < 2; ++kk) {
          int rgr = (4 * kk + quad) ^ (l16 & 7);
          bf16x8 ap = *reinterpret_cast<bf16x8*>(&sPt[wave][l16 * 64 + rgr * 8]);
#pragma unroll
          for (int jd = 0; jd < 4; ++jd)
            o_acc[s][jd] = __builtin_amdgcn_mfma_f32_16x16x32_bf16(
                ap, bv[kk][jd], o_acc[s][jd], 0, 0, 0);
        }
      }
    }

    if (hn) {  // commit prefetched tile (rope K here, overlapped w/ nothing)
      const int nb = buf ^ 1;
      float pk = (float)posn;
      *reinterpret_cast<bf16x8*>(&sK[nb][krow * LS + kc]) = rope8(kn0, pk, kp0a, 1.0f);
      *reinterpret_cast<bf16x8*>(&sK[nb][krow * LS + kc + 8]) = rope8(kn1, pk, kp0b, 1.0f);
#pragma unroll
      for (int c = 0; c < 8; ++c) {
        int u = c * 256 + tid;
        int d = u & 63, kvp = u >> 6;
        *reinterpret_cast<unsigned*>(&sVt[nb][d * LS + 2 * kvp]) = vw[c];
      }
    }
  }

  // epilogue: per-subtile l reduction (across quads) + normalize + store
#pragma unroll
  for (int s = 0; s < 2; ++s) {
    float l = l_run[s];
    l += __shfl_xor(l, 16);
    l += __shfl_xor(l, 32);  // every lane: total for q-row (lane&15)
    __hip_bfloat16* Aobase = Ao + (rowbase + sbs[s]) * D_MODEL + ho;
#pragma unroll
    for (int r = 0; r < 4; ++r) {
      float linv = 1.0f / __shfl(l, quad * 4 + r);  // lane n<16 holds row n
#pragma unroll
      for (int jd = 0; jd < 4; ++jd)
        Aobase[(size_t)(quad * 4 + r) * D_MODEL + jd * 16 + l16] =
            __float2bfloat16(o_acc[s][jd][r] * linv);
    }
  }
}

// ---------------- launch ----------------
extern "C" void kernel_launch(void* const* d_in, const int* in_sizes, int n_in,
                              void* d_out, int out_size, void* d_ws, size_t ws_size,
                              hipStream_t stream) {
  const float* x = (const float*)d_in[0];
  const float* wq = (const float*)d_in[1];
  const float* wk = (const float*)d_in[2];
  const float* wv = (const float*)d_in[3];
  const float* wo = (const float*)d_in[4];
  const int* tpos = (const int*)d_in[5];
  float* out = (float*)d_out;
  char* ws = (char*)d_ws;

  __hip_bfloat16* xb    = (__hip_bfloat16*)(ws);                      // 8 MiB
  __hip_bfloat16* wqkvb = (__hip_bfloat16*)(ws + (size_t)(8)  * 1048576); // 6
  __hip_bfloat16* wob   = (__hip_bfloat16*)(ws + (size_t)(14) * 1048576); // 2
  __hip_bfloat16* Qb    = (__hip_bfloat16*)(ws + (size_t)(16) * 1048576);
  __hip_bfloat16* Kb    = (__hip_bfloat16*)(ws + (size_t)(24) * 1048576);
  __hip_bfloat16* Vb    = (__hip_bfloat16*)(ws + (size_t)(32) * 1048576);
  __hip_bfloat16* Aob   = xb;  // x dead after QKV projection

  cvt_all_kernel<<<8192, 256, 0, stream>>>(x, wq, wk, wv, wo, xb, wqkvb, wob);

  gemm_qkv_kernel<<<dim3(32, 24), 256, 0, stream>>>(xb, wqkvb, Qb, Kb, Vb);

  attn_kernel<<<512, 256, 0, stream>>>(Qb, Kb, Vb, tpos, Aob);

  gemm_out_kernel<<<dim3(64, 8), 256, 0, stream>>>(Aob, wob, out);
}

// Round 7
// 205.615 us; speedup vs baseline: 1.2300x; 1.2300x over previous
//
#include <hip/hip_runtime.h>
#include <hip/hip_bf16.h>
#include <math.h>

#define D_MODEL 1024
#define NUM_HEADS 16
#define DK 64
#define BATCH 2
#define SEQ 2048
#define NROWS (BATCH * SEQ) /* 4096 */

typedef __bf16 bf16x8 __attribute__((ext_vector_type(8)));
typedef __bf16 bf16x4 __attribute__((ext_vector_type(4)));
typedef float f32x4 __attribute__((ext_vector_type(4)));

// async global->LDS, 16 B per lane; LDS dest = wave-uniform base + lane*16
#define GLOAD_LDS16(g, l)                                          \
  __builtin_amdgcn_global_load_lds(                                \
      (const __attribute__((address_space(1))) void*)(g),          \
      (__attribute__((address_space(3))) void*)(l), 16, 0, 0)

// LDS-only wait + compiler reorder fence (NO vmcnt drain — keeps global
// prefetch loads in flight)
#define LDS_FENCE() asm volatile("s_waitcnt lgkmcnt(0)" ::: "memory")

// ---------------- fused fp32 -> bf16 conversion ----------------------------
// wq/wk/wv packed contiguous into wqkvb (3072 x 1024); wo separate.
__global__ void cvt_all_kernel(const float* __restrict__ x,
                               const float* __restrict__ wq,
                               const float* __restrict__ wk,
                               const float* __restrict__ wv,
                               const float* __restrict__ wo,
                               __hip_bfloat16* __restrict__ xb,
                               __hip_bfloat16* __restrict__ wqkvb,
                               __hip_bfloat16* __restrict__ wob) {
  int t = blockIdx.x * 256 + threadIdx.x;  // 2,097,152 float4 units total
  const float* src;
  __hip_bfloat16* dst;
  int off;
  if (t < 1048576) {
    src = x; dst = xb; off = t;
  } else {
    int u = t - 1048576;
    int w = u >> 18;  // 262144 float4 per weight
    off = u & 262143;
    src = (w == 0) ? wq : (w == 1) ? wk : (w == 2) ? wv : wo;
    dst = (w < 3) ? (wqkvb + (size_t)w * 1048576) : wob;
  }
  float4 v = reinterpret_cast<const float4*>(src)[off];
  union { __hip_bfloat16 h[4]; uint2 u; } tmp;
  tmp.h[0] = __float2bfloat16(v.x);
  tmp.h[1] = __float2bfloat16(v.y);
  tmp.h[2] = __float2bfloat16(v.z);
  tmp.h[3] = __float2bfloat16(v.w);
  reinterpret_cast<uint2*>(dst)[off] = tmp.u;
}

// ---------------- QKV GEMM (m97 + 1-barrier dbuf) --------------------------
// C[m,n] = sum_k A[m,k] * W[n,k]; W packed (3072 rows) -> Q/K/V by n>>10.
__global__ __launch_bounds__(256)
void gemm_qkv_kernel(const __hip_bfloat16* __restrict__ A,
                     const __hip_bfloat16* __restrict__ W,
                     __hip_bfloat16* __restrict__ O0,
                     __hip_bfloat16* __restrict__ O1,
                     __hip_bfloat16* __restrict__ O2) {
  __shared__ __hip_bfloat16 sA[2][128 * 32];
  __shared__ __hip_bfloat16 sB[2][128 * 32];
  const int tid = threadIdx.x;
  const int wave = tid >> 6, lane = tid & 63, quad = lane >> 4, l16 = lane & 15;
  const int wm = (wave >> 1) * 64, wn = (wave & 1) * 64;
  const int bm = blockIdx.x * 128;
  const int bnG = blockIdx.y * 128;  // row base into packed W
  int which = blockIdx.y >> 3;
  __hip_bfloat16* O = (which == 0) ? O0 : (which == 1) ? O1 : O2;
  const int ocol = bnG & 1023;
  const int srow = lane >> 2, scol = (lane & 3) * 8;

#pragma unroll
  for (int c = 0; c < 2; ++c) {
    int ch = wave + c * 4;
    GLOAD_LDS16(&A[(size_t)(bm + ch * 16 + srow) * D_MODEL + scol], &sA[0][ch * 512]);
    GLOAD_LDS16(&W[(size_t)(bnG + ch * 16 + srow) * D_MODEL + scol], &sB[0][ch * 512]);
  }

  f32x4 acc[4][4] = {};
  for (int it = 0; it < 32; ++it) {
    __syncthreads();
    if (it + 1 < 32) {
      const int k0 = (it + 1) * 32, nb = (it + 1) & 1;
#pragma unroll
      for (int c = 0; c < 2; ++c) {
        int ch = wave + c * 4;
        GLOAD_LDS16(&A[(size_t)(bm + ch * 16 + srow) * D_MODEL + k0 + scol],
                    &sA[nb][ch * 512]);
        GLOAD_LDS16(&W[(size_t)(bnG + ch * 16 + srow) * D_MODEL + k0 + scol],
                    &sB[nb][ch * 512]);
      }
    }
    const int cb = it & 1;
    bf16x8 af[4], bfb[4];
#pragma unroll
    for (int i = 0; i < 4; ++i)
      af[i] = *reinterpret_cast<bf16x8*>(&sA[cb][(wm + i * 16 + l16) * 32 + quad * 8]);
#pragma unroll
    for (int j = 0; j < 4; ++j)
      bfb[j] = *reinterpret_cast<bf16x8*>(&sB[cb][(wn + j * 16 + l16) * 32 + quad * 8]);
#pragma unroll
    for (int i = 0; i < 4; ++i)
#pragma unroll
      for (int j = 0; j < 4; ++j)
        acc[i][j] = __builtin_amdgcn_mfma_f32_16x16x32_bf16(af[i], bfb[j], acc[i][j], 0, 0, 0);
  }

#pragma unroll
  for (int i = 0; i < 4; ++i)
#pragma unroll
    for (int j = 0; j < 4; ++j)
#pragma unroll
      for (int r = 0; r < 4; ++r) {
        int row = bm + wm + i * 16 + quad * 4 + r;
        int col = ocol + wn + j * 16 + l16;
        O[(size_t)row * D_MODEL + col] = __float2bfloat16(acc[i][j][r]);
      }
}

// ---------------- out-proj GEMM, 64x128 tile (512 blocks -> 2/CU) ----------
__global__ __launch_bounds__(256)
void gemm_out_kernel(const __hip_bfloat16* __restrict__ A,
                     const __hip_bfloat16* __restrict__ W,
                     float* __restrict__ O) {
  __shared__ __hip_bfloat16 sA[2][64 * 32];
  __shared__ __hip_bfloat16 sB[2][128 * 32];
  const int tid = threadIdx.x;
  const int wave = tid >> 6, lane = tid & 63, quad = lane >> 4, l16 = lane & 15;
  const int mh = (wave >> 1) * 32, nh = (wave & 1) * 64;
  const int bm = blockIdx.x * 64, bn = blockIdx.y * 128;
  const int srow = lane >> 2, scol = (lane & 3) * 8;

  GLOAD_LDS16(&A[(size_t)(bm + wave * 16 + srow) * D_MODEL + scol], &sA[0][wave * 512]);
#pragma unroll
  for (int c = 0; c < 2; ++c) {
    int ch = wave + c * 4;
    GLOAD_LDS16(&W[(size_t)(bn + ch * 16 + srow) * D_MODEL + scol], &sB[0][ch * 512]);
  }

  f32x4 acc[2][4] = {};
  for (int it = 0; it < 32; ++it) {
    __syncthreads();
    if (it + 1 < 32) {
      const int k0 = (it + 1) * 32, nb = (it + 1) & 1;
      GLOAD_LDS16(&A[(size_t)(bm + wave * 16 + srow) * D_MODEL + k0 + scol],
                  &sA[nb][wave * 512]);
#pragma unroll
      for (int c = 0; c < 2; ++c) {
        int ch = wave + c * 4;
        GLOAD_LDS16(&W[(size_t)(bn + ch * 16 + srow) * D_MODEL + k0 + scol],
                    &sB[nb][ch * 512]);
      }
    }
    const int cb = it & 1;
    bf16x8 af[2], bfb[4];
#pragma unroll
    for (int i = 0; i < 2; ++i)
      af[i] = *reinterpret_cast<bf16x8*>(&sA[cb][(mh + i * 16 + l16) * 32 + quad * 8]);
#pragma unroll
    for (int j = 0; j < 4; ++j)
      bfb[j] = *reinterpret_cast<bf16x8*>(&sB[cb][(nh + j * 16 + l16) * 32 + quad * 8]);
#pragma unroll
    for (int i = 0; i < 2; ++i)
#pragma unroll
      for (int j = 0; j < 4; ++j)
        acc[i][j] = __builtin_amdgcn_mfma_f32_16x16x32_bf16(af[i], bfb[j], acc[i][j], 0, 0, 0);
  }

#pragma unroll
  for (int i = 0; i < 2; ++i)
#pragma unroll
    for (int j = 0; j < 4; ++j)
#pragma unroll
      for (int r = 0; r < 4; ++r) {
        int row = bm + mh + i * 16 + quad * 4 + r;
        int col = bn + nh + j * 16 + l16;
        O[(size_t)row * D_MODEL + col] = acc[i][j][r];
      }
}

// ---------------- RoPE, vectorized; Q scaled by 0.125*log2(e) --------------
// Materialized ONCE per element (R=17 consumers per K tile in attn make
// recompute-in-attn a 2x regression — measured round 6).
__global__ void rope_kernel(__hip_bfloat16* __restrict__ Q,
                            __hip_bfloat16* __restrict__ K,
                            const int* __restrict__ pos) {
  constexpr float QS = 0.18033688011112042f;  // 0.125 * log2(e)
  int t = blockIdx.x * 256 + threadIdx.x;  // 524288 = 4096 rows * 128 chunks
  int row = t >> 7;
  int c = t & 127;
  int h = c >> 3, co = (c & 7) * 8;
  float ps = (float)pos[row];
  size_t off = (size_t)row * D_MODEL + h * DK + co;
  bf16x8 q = *reinterpret_cast<const bf16x8*>(&Q[off]);
  bf16x8 k = *reinterpret_cast<const bf16x8*>(&K[off]);
#pragma unroll
  for (int j = 0; j < 4; ++j) {
    float p = (float)((co >> 1) + j);
    float ang = ps * exp2f(-p * 0.41524101186091903f);  // 10000^(-p/32)
    float cs = cosf(ang), sn = sinf(ang);
    float qe = (float)q[2 * j], qo = (float)q[2 * j + 1];
    q[2 * j]     = (__bf16)((qe * cs - qo * sn) * QS);
    q[2 * j + 1] = (__bf16)((qe * sn + qo * cs) * QS);
    float ke = (float)k[2 * j], ko = (float)k[2 * j + 1];
    k[2 * j]     = (__bf16)(ke * cs - ko * sn);
    k[2 * j + 1] = (__bf16)(ke * sn + ko * cs);
  }
  *reinterpret_cast<bf16x8*>(&Q[off]) = q;
  *reinterpret_cast<bf16x8*>(&K[off]) = k;
}

// ---------------- Flash attention (causal), balanced blocks ----------------
// 256 thd = 4 waves; 512 BALANCED blocks: block = (pair pi, half, b, h).
// q-groups qlo=pi and qhi=15-pi share one kv stream; wave w owns subtile
// jL = half*4+w of qlo-group and jU = 7-jL of qhi-group -> constant
// tile-visits per wave, zero tail. S^T orientation (K=A, Q=B: K/V frags
// q-independent, read once per tile), XOR-swizzled sPt (conflict-free),
// no max-subtraction (logits ~N(0,1); exp2 in fp32), dbuf staging with
// register prefetch, one barrier per kv-tile.
__global__ __launch_bounds__(256)
void attn_kernel(const __hip_bfloat16* __restrict__ Q,
                 const __hip_bfloat16* __restrict__ K,
                 const __hip_bfloat16* __restrict__ V,
                 __hip_bfloat16* __restrict__ Ao) {
  constexpr int LS = 66;  // sK/sVt stride (33 dwords, odd -> bank spread)
  __shared__ __hip_bfloat16 sK[2][64 * LS];
  __shared__ __hip_bfloat16 sVt[2][64 * LS];  // sVt[d][kv]
  __shared__ __hip_bfloat16 sPt[4][16 * 64];  // per-wave, XOR-swizzled
  const int tid = threadIdx.x;
  const int wave = tid >> 6, lane = tid & 63, quad = lane >> 4, l16 = lane & 15;
  const int idx = blockIdx.x;            // 512 blocks, all equal work
  const int bh = idx & 31;
  const int half = (idx >> 5) & 1;
  const int pi = idx >> 6;               // 0..7
  const int qlo = pi, qhi = 15 - pi;
  const int h = bh & 15, b = bh >> 4;
  const int ho = h * DK;
  const size_t rowbase = (size_t)b * SEQ;
  const int jL = half * 4 + wave, jU = 7 - jL;
  const int sbs[2] = {qlo * 128 + jL * 16, qhi * 128 + jU * 16};  // sbs[1]>sbs[0]
  // stream length: block's largest subtile is wave 0's jU
  const int nt = ((qhi * 128 + (7 - half * 4) * 16 + 15) >> 6) + 1;
  const __hip_bfloat16* Kbase = K + rowbase * D_MODEL + ho;
  const unsigned short* Vu =
      reinterpret_cast<const unsigned short*>(V + rowbase * D_MODEL + ho);

  // Q fragments (B-operand; lane l16 = q-row; 0.125*log2e pre-folded)
  bf16x8 aq[2][2];
#pragma unroll
  for (int s = 0; s < 2; ++s)
#pragma unroll
    for (int kk = 0; kk < 2; ++kk)
      aq[s][kk] = *reinterpret_cast<const bf16x8*>(
          &Q[(rowbase + sbs[s] + l16) * D_MODEL + ho + kk * 32 + quad * 8]);

  f32x4 o_acc[2][4] = {};
  float l_run[2] = {0.f, 0.f};

  // staging maps: K: row = tid>>2, two b128 chunks at (tid&3)*16
  const int krow = tid >> 2, kc = (tid & 3) * 16;

  // prologue: stage tile 0 into buffer 0
  {
    *reinterpret_cast<bf16x8*>(&sK[0][krow * LS + kc]) =
        *reinterpret_cast<const bf16x8*>(&Kbase[(size_t)krow * D_MODEL + kc]);
    *reinterpret_cast<bf16x8*>(&sK[0][krow * LS + kc + 8]) =
        *reinterpret_cast<const bf16x8*>(&Kbase[(size_t)krow * D_MODEL + kc + 8]);
#pragma unroll
    for (int c = 0; c < 8; ++c) {
      int u = c * 256 + tid;  // 2048 units = 64 d x 32 kv-pairs
      int d = u & 63, kvp = u >> 6;
      unsigned lo = Vu[(size_t)(2 * kvp) * D_MODEL + d];
      unsigned hi = Vu[(size_t)(2 * kvp + 1) * D_MODEL + d];
      *reinterpret_cast<unsigned*>(&sVt[0][d * LS + 2 * kvp]) = lo | (hi << 16);
    }
  }

  for (int t = 0; t < nt; ++t) {
    __syncthreads();  // staging for tile t visible
    const int buf = t & 1;
    const bool hn = (t + 1) < nt;
    bf16x8 kn0, kn1;
    unsigned vw[8];
    if (hn) {  // register prefetch of next tile (latency overlapped)
      const int kvn = (t + 1) * 64;
      kn0 = *reinterpret_cast<const bf16x8*>(
          &Kbase[(size_t)(kvn + krow) * D_MODEL + kc]);
      kn1 = *reinterpret_cast<const bf16x8*>(
          &Kbase[(size_t)(kvn + krow) * D_MODEL + kc + 8]);
#pragma unroll
      for (int c = 0; c < 8; ++c) {
        int u = c * 256 + tid;
        int d = u & 63, kvp = u >> 6;
        unsigned lo = Vu[(size_t)(kvn + 2 * kvp) * D_MODEL + d];
        unsigned hi = Vu[(size_t)(kvn + 2 * kvp + 1) * D_MODEL + d];
        vw[c] = lo | (hi << 16);
      }
    }

    const int kv0 = t * 64;
    if (kv0 <= sbs[1] + 15) {
      // q-independent fragments: load ONCE, reuse for both subtiles
      bf16x8 ak[2][4], bv[2][4];
#pragma unroll
      for (int kk = 0; kk < 2; ++kk)
#pragma unroll
        for (int j = 0; j < 4; ++j) {
          ak[kk][j] = *reinterpret_cast<bf16x8*>(
              &sK[buf][(j * 16 + l16) * LS + kk * 32 + quad * 8]);
          bv[kk][j] = *reinterpret_cast<bf16x8*>(
              &sVt[buf][(j * 16 + l16) * LS + kk * 32 + quad * 8]);
        }

#pragma unroll
      for (int s = 0; s < 2; ++s) {
        const int sb = sbs[s];
        if (kv0 > sb + 15) continue;
        // S^T = K Q^T : lane holds S[q=sb+l16][kv0 + 16j + 4quad + r]
        f32x4 sv[4] = {};
#pragma unroll
        for (int kk = 0; kk < 2; ++kk)
#pragma unroll
          for (int j = 0; j < 4; ++j)
            sv[j] = __builtin_amdgcn_mfma_f32_16x16x32_bf16(ak[kk][j], aq[s][kk],
                                                            sv[j], 0, 0, 0);
        // Causal mask (diagonal-crossing tiles only)
        if (kv0 + 63 > sb) {
#pragma unroll
          for (int j = 0; j < 4; ++j)
#pragma unroll
            for (int r = 0; r < 4; ++r)
              if (kv0 + j * 16 + quad * 4 + r > sb + l16) sv[j][r] = -INFINITY;
        }
        // exp2; in-lane row-sum; write P rows (q=l16) XOR-swizzled, b64
        float ls = 0.f;
#pragma unroll
        for (int j = 0; j < 4; ++j) {
          bf16x4 pk;
#pragma unroll
          for (int r = 0; r < 4; ++r) {
            float p = __builtin_amdgcn_exp2f(sv[j][r]);
            ls += p;
            pk[r] = (__bf16)p;
          }
          int wgr = (2 * j + (quad >> 1)) ^ (l16 & 7);  // 4-dword granule
          *reinterpret_cast<bf16x4*>(
              &sPt[wave][l16 * 64 + wgr * 8 + (quad & 1) * 4]) = pk;
        }
        l_run[s] += ls;
        LDS_FENCE();  // order sPt write->read (same wave); vmcnt untouched
        // O += P V
#pragma unroll
        for (int kk = 0; kk < 2; ++kk) {
          int rgr = (4 * kk + quad) ^ (l16 & 7);
          bf16x8 ap = *reinterpret_cast<bf16x8*>(&sPt[wave][l16 * 64 + rgr * 8]);
#pragma unroll
          for (int jd = 0; jd < 4; ++jd)
            o_acc[s][jd] = __builtin_amdgcn_mfma_f32_16x16x32_bf16(
                ap, bv[kk][jd], o_acc[s][jd], 0, 0, 0);
        }
      }
    }

    if (hn) {  // commit prefetched tile into the other buffer
      const int nb = buf ^ 1;
      *reinterpret_cast<bf16x8*>(&sK[nb][krow * LS + kc]) = kn0;
      *reinterpret_cast<bf16x8*>(&sK[nb][krow * LS + kc + 8]) = kn1;
#pragma unroll
      for (int c = 0; c < 8; ++c) {
        int u = c * 256 + tid;
        int d = u & 63, kvp = u >> 6;
        *reinterpret_cast<unsigned*>(&sVt[nb][d * LS + 2 * kvp]) = vw[c];
      }
    }
  }

  // epilogue: per-subtile l reduction (across quads) + normalize + store
#pragma unroll
  for (int s = 0; s < 2; ++s) {
    float l = l_run[s];
    l += __shfl_xor(l, 16);
    l += __shfl_xor(l, 32);  // every lane: total for q-row (lane&15)
    __hip_bfloat16* Aobase = Ao + (rowbase + sbs[s]) * D_MODEL + ho;
#pragma unroll
    for (int r = 0; r < 4; ++r) {
      float linv = 1.0f / __shfl(l, quad * 4 + r);  // lane n<16 holds row n
#pragma unroll
      for (int jd = 0; jd < 4; ++jd)
        Aobase[(size_t)(quad * 4 + r) * D_MODEL + jd * 16 + l16] =
            __float2bfloat16(o_acc[s][jd][r] * linv);
    }
  }
}

// ---------------- launch ----------------
extern "C" void kernel_launch(void* const* d_in, const int* in_sizes, int n_in,
                              void* d_out, int out_size, void* d_ws, size_t ws_size,
                              hipStream_t stream) {
  const float* x = (const float*)d_in[0];
  const float* wq = (const float*)d_in[1];
  const float* wk = (const float*)d_in[2];
  const float* wv = (const float*)d_in[3];
  const float* wo = (const float*)d_in[4];
  const int* tpos = (const int*)d_in[5];
  float* out = (float*)d_out;
  char* ws = (char*)d_ws;

  __hip_bfloat16* xb    = (__hip_bfloat16*)(ws);                      // 8 MiB
  __hip_bfloat16* wqkvb = (__hip_bfloat16*)(ws + (size_t)(8)  * 1048576); // 6
  __hip_bfloat16* wob   = (__hip_bfloat16*)(ws + (size_t)(14) * 1048576); // 2
  __hip_bfloat16* Qb    = (__hip_bfloat16*)(ws + (size_t)(16) * 1048576);
  __hip_bfloat16* Kb    = (__hip_bfloat16*)(ws + (size_t)(24) * 1048576);
  __hip_bfloat16* Vb    = (__hip_bfloat16*)(ws + (size_t)(32) * 1048576);
  __hip_bfloat16* Aob   = xb;  // x dead after QKV projection

  cvt_all_kernel<<<8192, 256, 0, stream>>>(x, wq, wk, wv, wo, xb, wqkvb, wob);

  gemm_qkv_kernel<<<dim3(32, 24), 256, 0, stream>>>(xb, wqkvb, Qb, Kb, Vb);

  rope_kernel<<<2048, 256, 0, stream>>>(Qb, Kb, tpos);

  attn_kernel<<<512, 256, 0, stream>>>(Qb, Kb, Vb, Aob);

  gemm_out_kernel<<<dim3(64, 8), 256, 0, stream>>>(Aob, wob, out);
}

// Round 8
// 182.373 us; speedup vs baseline: 1.3868x; 1.1274x over previous
//
#include <hip/hip_runtime.h>
#include <hip/hip_bf16.h>
#include <math.h>

#define D_MODEL 1024
#define NUM_HEADS 16
#define DK 64
#define BATCH 2
#define SEQ 2048
#define NROWS (BATCH * SEQ) /* 4096 */

typedef __bf16 bf16x8 __attribute__((ext_vector_type(8)));
typedef __bf16 bf16x4 __attribute__((ext_vector_type(4)));
typedef float f32x4 __attribute__((ext_vector_type(4)));

// async global->LDS, 16 B per lane; LDS dest = wave-uniform base + lane*16
#define GLOAD_LDS16(g, l)                                          \
  __builtin_amdgcn_global_load_lds(                                \
      (const __attribute__((address_space(1))) void*)(g),          \
      (__attribute__((address_space(3))) void*)(l), 16, 0, 0)

// LDS-only wait + compiler reorder fence (NO vmcnt drain)
#define LDS_FENCE() asm volatile("s_waitcnt lgkmcnt(0)" ::: "memory")

// ---------------- fused fp32 -> bf16 conversion ----------------------------
__global__ void cvt_all_kernel(const float* __restrict__ x,
                               const float* __restrict__ wq,
                               const float* __restrict__ wk,
                               const float* __restrict__ wv,
                               const float* __restrict__ wo,
                               __hip_bfloat16* __restrict__ xb,
                               __hip_bfloat16* __restrict__ wqkvb,
                               __hip_bfloat16* __restrict__ wob) {
  int t = blockIdx.x * 256 + threadIdx.x;  // 2,097,152 float4 units total
  const float* src;
  __hip_bfloat16* dst;
  int off;
  if (t < 1048576) {
    src = x; dst = xb; off = t;
  } else {
    int u = t - 1048576;
    int w = u >> 18;  // 262144 float4 per weight
    off = u & 262143;
    src = (w == 0) ? wq : (w == 1) ? wk : (w == 2) ? wv : wo;
    dst = (w < 3) ? (wqkvb + (size_t)w * 1048576) : wob;
  }
  float4 v = reinterpret_cast<const float4*>(src)[off];
  union { __hip_bfloat16 h[4]; uint2 u; } tmp;
  tmp.h[0] = __float2bfloat16(v.x);
  tmp.h[1] = __float2bfloat16(v.y);
  tmp.h[2] = __float2bfloat16(v.z);
  tmp.h[3] = __float2bfloat16(v.w);
  reinterpret_cast<uint2*>(dst)[off] = tmp.u;
}

// ---------------- QKV GEMM (m97 + 1-barrier dbuf) --------------------------
// C[m,n] = sum_k A[m,k] * W[n,k]; W packed (3072 rows).
// which 0/1 -> Q/K row-major; which 2 -> V written TRANSPOSED to
// Vt[((b*16+h)*64+d)][s] via an LDS transpose (XOR-swizzled, conflict-free).
__global__ __launch_bounds__(256)
void gemm_qkv_kernel(const __hip_bfloat16* __restrict__ A,
                     const __hip_bfloat16* __restrict__ W,
                     __hip_bfloat16* __restrict__ O0,
                     __hip_bfloat16* __restrict__ O1,
                     __hip_bfloat16* __restrict__ Vt) {
  __shared__ __hip_bfloat16 smem[2][2][128 * 32];  // [A/B][buf]; 32 KB
#define sAg(b) (smem[0][b])
#define sBg(b) (smem[1][b])
  const int tid = threadIdx.x;
  const int wave = tid >> 6, lane = tid & 63, quad = lane >> 4, l16 = lane & 15;
  const int wm = (wave >> 1) * 64, wn = (wave & 1) * 64;
  const int bm = blockIdx.x * 128;
  const int bnG = blockIdx.y * 128;  // row base into packed W
  const int which = blockIdx.y >> 3;
  const int ocol = bnG & 1023;
  const int srow = lane >> 2, scol = (lane & 3) * 8;

#pragma unroll
  for (int c = 0; c < 2; ++c) {
    int ch = wave + c * 4;
    GLOAD_LDS16(&A[(size_t)(bm + ch * 16 + srow) * D_MODEL + scol], &sAg(0)[ch * 512]);
    GLOAD_LDS16(&W[(size_t)(bnG + ch * 16 + srow) * D_MODEL + scol], &sBg(0)[ch * 512]);
  }

  f32x4 acc[4][4] = {};
  for (int it = 0; it < 32; ++it) {
    __syncthreads();
    if (it + 1 < 32) {
      const int k0 = (it + 1) * 32, nb = (it + 1) & 1;
#pragma unroll
      for (int c = 0; c < 2; ++c) {
        int ch = wave + c * 4;
        GLOAD_LDS16(&A[(size_t)(bm + ch * 16 + srow) * D_MODEL + k0 + scol],
                    &sAg(nb)[ch * 512]);
        GLOAD_LDS16(&W[(size_t)(bnG + ch * 16 + srow) * D_MODEL + k0 + scol],
                    &sBg(nb)[ch * 512]);
      }
    }
    const int cb = it & 1;
    bf16x8 af[4], bfb[4];
#pragma unroll
    for (int i = 0; i < 4; ++i)
      af[i] = *reinterpret_cast<bf16x8*>(&sAg(cb)[(wm + i * 16 + l16) * 32 + quad * 8]);
#pragma unroll
    for (int j = 0; j < 4; ++j)
      bfb[j] = *reinterpret_cast<bf16x8*>(&sBg(cb)[(wn + j * 16 + l16) * 32 + quad * 8]);
#pragma unroll
    for (int i = 0; i < 4; ++i)
#pragma unroll
      for (int j = 0; j < 4; ++j)
        acc[i][j] = __builtin_amdgcn_mfma_f32_16x16x32_bf16(af[i], bfb[j], acc[i][j], 0, 0, 0);
  }

  // C/D layout: col = lane&15, row = quad*4 + reg   [measured m89/m91]
  if (which < 2) {
    __hip_bfloat16* O = (which == 0) ? O0 : O1;
#pragma unroll
    for (int i = 0; i < 4; ++i)
#pragma unroll
      for (int j = 0; j < 4; ++j)
#pragma unroll
        for (int r = 0; r < 4; ++r) {
          int row = bm + wm + i * 16 + quad * 4 + r;
          int col = ocol + wn + j * 16 + l16;
          O[(size_t)row * D_MODEL + col] = __float2bfloat16(acc[i][j][r]);
        }
  } else {
    // V-transpose epilogue: 128x128 tile -> LDS (swizzled) -> Vt coalesced.
    __syncthreads();  // all waves done with sA/sB MFMA reads
    __hip_bfloat16* tr = &smem[0][0][0];  // 128 x 128 bf16 = 32 KB
    // write: c = local col (v-dim), r = local row (token); granule (r>>3)
    // stored at (r>>3)^(c&15); b64 (4 consecutive r in-lane) conflict-free.
#pragma unroll
    for (int i = 0; i < 4; ++i)
#pragma unroll
      for (int j = 0; j < 4; ++j) {
        int c = wn + j * 16 + l16;
        int r = wm + i * 16 + quad * 4;
        bf16x4 pk;
#pragma unroll
        for (int rr = 0; rr < 4; ++rr) pk[rr] = (__bf16)acc[i][j][rr];
        int g = (r >> 3) ^ (c & 15);
        *reinterpret_cast<bf16x4*>(&tr[c * 128 + g * 8 + (r & 7)]) = pk;
      }
    __syncthreads();
    // read rows of transposed tile, store contiguous-in-s to Vt
    int c = tid >> 1;
    int vcol = ocol + c;  // global v-dim 0..1023
    int hh = vcol >> 6, dd = vcol & 63;
    int bb = bm >> 11, s0 = (bm & 2047) + (tid & 1) * 64;
    __hip_bfloat16* dst = Vt + ((size_t)(bb * 16 + hh) * 64 + dd) * 2048 + s0;
    int gbase = (tid & 1) * 8;
#pragma unroll
    for (int k = 0; k < 8; ++k) {
      int g = (gbase + k) ^ (c & 15);
      *reinterpret_cast<bf16x8*>(&dst[k * 8]) =
          *reinterpret_cast<bf16x8*>(&tr[c * 128 + g * 8]);
    }
  }
#undef sAg
#undef sBg
}

// ---------------- out-proj GEMM, 64x128 tile (512 blocks -> 2/CU) ----------
__global__ __launch_bounds__(256)
void gemm_out_kernel(const __hip_bfloat16* __restrict__ A,
                     const __hip_bfloat16* __restrict__ W,
                     float* __restrict__ O) {
  __shared__ __hip_bfloat16 sA[2][64 * 32];
  __shared__ __hip_bfloat16 sB[2][128 * 32];
  const int tid = threadIdx.x;
  const int wave = tid >> 6, lane = tid & 63, quad = lane >> 4, l16 = lane & 15;
  const int mh = (wave >> 1) * 32, nh = (wave & 1) * 64;
  const int bm = blockIdx.x * 64, bn = blockIdx.y * 128;
  const int srow = lane >> 2, scol = (lane & 3) * 8;

  GLOAD_LDS16(&A[(size_t)(bm + wave * 16 + srow) * D_MODEL + scol], &sA[0][wave * 512]);
#pragma unroll
  for (int c = 0; c < 2; ++c) {
    int ch = wave + c * 4;
    GLOAD_LDS16(&W[(size_t)(bn + ch * 16 + srow) * D_MODEL + scol], &sB[0][ch * 512]);
  }

  f32x4 acc[2][4] = {};
  for (int it = 0; it < 32; ++it) {
    __syncthreads();
    if (it + 1 < 32) {
      const int k0 = (it + 1) * 32, nb = (it + 1) & 1;
      GLOAD_LDS16(&A[(size_t)(bm + wave * 16 + srow) * D_MODEL + k0 + scol],
                  &sA[nb][wave * 512]);
#pragma unroll
      for (int c = 0; c < 2; ++c) {
        int ch = wave + c * 4;
        GLOAD_LDS16(&W[(size_t)(bn + ch * 16 + srow) * D_MODEL + k0 + scol],
                    &sB[nb][ch * 512]);
      }
    }
    const int cb = it & 1;
    bf16x8 af[2], bfb[4];
#pragma unroll
    for (int i = 0; i < 2; ++i)
      af[i] = *reinterpret_cast<bf16x8*>(&sA[cb][(mh + i * 16 + l16) * 32 + quad * 8]);
#pragma unroll
    for (int j = 0; j < 4; ++j)
      bfb[j] = *reinterpret_cast<bf16x8*>(&sB[cb][(nh + j * 16 + l16) * 32 + quad * 8]);
#pragma unroll
    for (int i = 0; i < 2; ++i)
#pragma unroll
      for (int j = 0; j < 4; ++j)
        acc[i][j] = __builtin_amdgcn_mfma_f32_16x16x32_bf16(af[i], bfb[j], acc[i][j], 0, 0, 0);
  }

#pragma unroll
  for (int i = 0; i < 2; ++i)
#pragma unroll
    for (int j = 0; j < 4; ++j)
#pragma unroll
      for (int r = 0; r < 4; ++r) {
        int row = bm + mh + i * 16 + quad * 4 + r;
        int col = bn + nh + j * 16 + l16;
        O[(size_t)row * D_MODEL + col] = acc[i][j][r];
      }
}

// ---------------- RoPE, vectorized; Q scaled by 0.125*log2(e) --------------
__global__ void rope_kernel(__hip_bfloat16* __restrict__ Q,
                            __hip_bfloat16* __restrict__ K,
                            const int* __restrict__ pos) {
  constexpr float QS = 0.18033688011112042f;  // 0.125 * log2(e)
  int t = blockIdx.x * 256 + threadIdx.x;  // 524288 = 4096 rows * 128 chunks
  int row = t >> 7;
  int c = t & 127;
  int h = c >> 3, co = (c & 7) * 8;
  float ps = (float)pos[row];
  size_t off = (size_t)row * D_MODEL + h * DK + co;
  bf16x8 q = *reinterpret_cast<const bf16x8*>(&Q[off]);
  bf16x8 k = *reinterpret_cast<const bf16x8*>(&K[off]);
#pragma unroll
  for (int j = 0; j < 4; ++j) {
    float p = (float)((co >> 1) + j);
    float ang = ps * exp2f(-p * 0.41524101186091903f);  // 10000^(-p/32)
    float cs = cosf(ang), sn = sinf(ang);
    float qe = (float)q[2 * j], qo = (float)q[2 * j + 1];
    q[2 * j]     = (__bf16)((qe * cs - qo * sn) * QS);
    q[2 * j + 1] = (__bf16)((qe * sn + qo * cs) * QS);
    float ke = (float)k[2 * j], ko = (float)k[2 * j + 1];
    k[2 * j]     = (__bf16)(ke * cs - ko * sn);
    k[2 * j + 1] = (__bf16)(ke * sn + ko * cs);
  }
  *reinterpret_cast<bf16x8*>(&Q[off]) = q;
  *reinterpret_cast<bf16x8*>(&K[off]) = k;
}

// ---------------- Flash attention (causal), balanced + swizzled ------------
// 256 thd = 4 waves; 512 balanced blocks (pair qlo=pi with qhi=15-pi).
// S^T orientation; K and V^T staged into XOR-granule-swizzled LDS
// (stride 64, granule g at g^(row&7)): fragment reads AND staging writes
// are uniform 8-lanes-per-bank -> conflict-free. V read from pre-transposed
// Vt (2 b128 loads/thread/tile; no scalar gather). Dbuf + register prefetch,
// one barrier per kv-tile, no max-subtraction, XOR-swizzled sPt.
__global__ __launch_bounds__(256)
void attn_kernel(const __hip_bfloat16* __restrict__ Q,
                 const __hip_bfloat16* __restrict__ K,
                 const __hip_bfloat16* __restrict__ Vt,
                 __hip_bfloat16* __restrict__ Ao) {
  __shared__ __hip_bfloat16 sK[2][64 * 64];
  __shared__ __hip_bfloat16 sVt[2][64 * 64];  // [d][kv], swizzled
  __shared__ __hip_bfloat16 sPt[4][16 * 64];  // per-wave, swizzled
  const int tid = threadIdx.x;
  const int wave = tid >> 6, lane = tid & 63, quad = lane >> 4, l16 = lane & 15;
  const int idx = blockIdx.x;            // 512 blocks, all equal work
  const int bh = idx & 31;
  const int half = (idx >> 5) & 1;
  const int pi = idx >> 6;               // 0..7
  const int qlo = pi, qhi = 15 - pi;
  const int h = bh & 15, b = bh >> 4;
  const int ho = h * DK;
  const size_t rowbase = (size_t)b * SEQ;
  const int jL = half * 4 + wave, jU = 7 - jL;
  const int sbs[2] = {qlo * 128 + jL * 16, qhi * 128 + jU * 16};  // sbs[1]>sbs[0]
  const int nt = ((qhi * 128 + (7 - half * 4) * 16 + 15) >> 6) + 1;
  const __hip_bfloat16* Kbase = K + rowbase * D_MODEL + ho;
  const __hip_bfloat16* Vtbase = Vt + (size_t)(b * 16 + h) * 64 * 2048;

  // Q fragments (B-operand; lane l16 = q-row; 0.125*log2e pre-folded)
  bf16x8 aq[2][2];
#pragma unroll
  for (int s = 0; s < 2; ++s)
#pragma unroll
    for (int kk = 0; kk < 2; ++kk)
      aq[s][kk] = *reinterpret_cast<const bf16x8*>(
          &Q[(rowbase + sbs[s] + l16) * D_MODEL + ho + kk * 32 + quad * 8]);

  f32x4 o_acc[2][4] = {};
  float l_run[2] = {0.f, 0.f};

  // staging maps: row = tid>>2 (64 rows), granules ga,ga+1 (= (tid&3)*2)
  const int srow = tid >> 2, sc = (tid & 3) * 16;
  const int ga = (tid & 3) * 2;
  const int sga = (ga ^ (srow & 7)) * 8, sgb = ((ga + 1) ^ (srow & 7)) * 8;

  // prologue: stage tile 0 into buffer 0
  {
    bf16x8 k0 = *reinterpret_cast<const bf16x8*>(&Kbase[(size_t)srow * D_MODEL + sc]);
    bf16x8 k1 = *reinterpret_cast<const bf16x8*>(&Kbase[(size_t)srow * D_MODEL + sc + 8]);
    bf16x8 v0 = *reinterpret_cast<const bf16x8*>(&Vtbase[(size_t)srow * 2048 + sc]);
    bf16x8 v1 = *reinterpret_cast<const bf16x8*>(&Vtbase[(size_t)srow * 2048 + sc + 8]);
    *reinterpret_cast<bf16x8*>(&sK[0][srow * 64 + sga]) = k0;
    *reinterpret_cast<bf16x8*>(&sK[0][srow * 64 + sgb]) = k1;
    *reinterpret_cast<bf16x8*>(&sVt[0][srow * 64 + sga]) = v0;
    *reinterpret_cast<bf16x8*>(&sVt[0][srow * 64 + sgb]) = v1;
  }

  for (int t = 0; t < nt; ++t) {
    __syncthreads();  // staging for tile t visible
    const int buf = t & 1;
    const bool hn = (t + 1) < nt;
    bf16x8 kn0, kn1, vn0, vn1;
    if (hn) {  // register prefetch of next tile (latency overlapped)
      const int kvn = (t + 1) * 64;
      kn0 = *reinterpret_cast<const bf16x8*>(
          &Kbase[(size_t)(kvn + srow) * D_MODEL + sc]);
      kn1 = *reinterpret_cast<const bf16x8*>(
          &Kbase[(size_t)(kvn + srow) * D_MODEL + sc + 8]);
      vn0 = *reinterpret_cast<const bf16x8*>(
          &Vtbase[(size_t)srow * 2048 + kvn + sc]);
      vn1 = *reinterpret_cast<const bf16x8*>(
          &Vtbase[(size_t)srow * 2048 + kvn + sc + 8]);
    }

    const int kv0 = t * 64;
    if (kv0 <= sbs[1] + 15) {
      // q-independent fragments: load once, reuse for both subtiles.
      // granule 4kk+quad of row (j*16+l16) at swizzled pos ^(l16&7).
      bf16x8 ak[2][4], bv[2][4];
#pragma unroll
      for (int kk = 0; kk < 2; ++kk)
#pragma unroll
        for (int j = 0; j < 4; ++j) {
          int go = ((4 * kk + quad) ^ (l16 & 7)) * 8;
          ak[kk][j] = *reinterpret_cast<bf16x8*>(&sK[buf][(j * 16 + l16) * 64 + go]);
          bv[kk][j] = *reinterpret_cast<bf16x8*>(&sVt[buf][(j * 16 + l16) * 64 + go]);
        }

#pragma unroll
      for (int s = 0; s < 2; ++s) {
        const int sb = sbs[s];
        if (kv0 > sb + 15) continue;
        // S^T = K Q^T : lane holds S[q=sb+l16][kv0 + 16j + 4quad + r]
        f32x4 sv[4] = {};
#pragma unroll
        for (int kk = 0; kk < 2; ++kk)
#pragma unroll
          for (int j = 0; j < 4; ++j)
            sv[j] = __builtin_amdgcn_mfma_f32_16x16x32_bf16(ak[kk][j], aq[s][kk],
                                                            sv[j], 0, 0, 0);
        // Causal mask (diagonal-crossing tiles only)
        if (kv0 + 63 > sb) {
#pragma unroll
          for (int j = 0; j < 4; ++j)
#pragma unroll
            for (int r = 0; r < 4; ++r)
              if (kv0 + j * 16 + quad * 4 + r > sb + l16) sv[j][r] = -INFINITY;
        }
        // exp2; in-lane row-sum; write P rows (q=l16) XOR-swizzled, b64
        float ls = 0.f;
#pragma unroll
        for (int j = 0; j < 4; ++j) {
          bf16x4 pk;
#pragma unroll
          for (int r = 0; r < 4; ++r) {
            float p = __builtin_amdgcn_exp2f(sv[j][r]);
            ls += p;
            pk[r] = (__bf16)p;
          }
          int wgr = (2 * j + (quad >> 1)) ^ (l16 & 7);  // 4-dword granule
          *reinterpret_cast<bf16x4*>(
              &sPt[wave][l16 * 64 + wgr * 8 + (quad & 1) * 4]) = pk;
        }
        l_run[s] += ls;
        LDS_FENCE();  // order sPt write->read (same wave); vmcnt untouched
        // O += P V
#pragma unroll
        for (int kk = 0; kk < 2; ++kk) {
          int rgr = (4 * kk + quad) ^ (l16 & 7);
          bf16x8 ap = *reinterpret_cast<bf16x8*>(&sPt[wave][l16 * 64 + rgr * 8]);
#pragma unroll
          for (int jd = 0; jd < 4; ++jd)
            o_acc[s][jd] = __builtin_amdgcn_mfma_f32_16x16x32_bf16(
                ap, bv[kk][jd], o_acc[s][jd], 0, 0, 0);
        }
      }
    }

    if (hn) {  // commit prefetched tile into the other buffer (swizzled)
      const int nb = buf ^ 1;
      *reinterpret_cast<bf16x8*>(&sK[nb][srow * 64 + sga]) = kn0;
      *reinterpret_cast<bf16x8*>(&sK[nb][srow * 64 + sgb]) = kn1;
      *reinterpret_cast<bf16x8*>(&sVt[nb][srow * 64 + sga]) = vn0;
      *reinterpret_cast<bf16x8*>(&sVt[nb][srow * 64 + sgb]) = vn1;
    }
  }

  // epilogue: per-subtile l reduction (across quads) + normalize + store
#pragma unroll
  for (int s = 0; s < 2; ++s) {
    float l = l_run[s];
    l += __shfl_xor(l, 16);
    l += __shfl_xor(l, 32);  // every lane: total for q-row (lane&15)
    __hip_bfloat16* Aobase = Ao + (rowbase + sbs[s]) * D_MODEL + ho;
#pragma unroll
    for (int r = 0; r < 4; ++r) {
      float linv = 1.0f / __shfl(l, quad * 4 + r);  // lane n<16 holds row n
#pragma unroll
      for (int jd = 0; jd < 4; ++jd)
        Aobase[(size_t)(quad * 4 + r) * D_MODEL + jd * 16 + l16] =
            __float2bfloat16(o_acc[s][jd][r] * linv);
    }
  }
}

// ---------------- launch ----------------
extern "C" void kernel_launch(void* const* d_in, const int* in_sizes, int n_in,
                              void* d_out, int out_size, void* d_ws, size_t ws_size,
                              hipStream_t stream) {
  const float* x = (const float*)d_in[0];
  const float* wq = (const float*)d_in[1];
  const float* wk = (const float*)d_in[2];
  const float* wv = (const float*)d_in[3];
  const float* wo = (const float*)d_in[4];
  const int* tpos = (const int*)d_in[5];
  float* out = (float*)d_out;
  char* ws = (char*)d_ws;

  __hip_bfloat16* xb    = (__hip_bfloat16*)(ws);                      // 8 MiB
  __hip_bfloat16* wqkvb = (__hip_bfloat16*)(ws + (size_t)(8)  * 1048576); // 6
  __hip_bfloat16* wob   = (__hip_bfloat16*)(ws + (size_t)(14) * 1048576); // 2
  __hip_bfloat16* Qb    = (__hip_bfloat16*)(ws + (size_t)(16) * 1048576);
  __hip_bfloat16* Kb    = (__hip_bfloat16*)(ws + (size_t)(24) * 1048576);
  __hip_bfloat16* Vtb   = (__hip_bfloat16*)(ws + (size_t)(32) * 1048576);
  __hip_bfloat16* Aob   = xb;  // x dead after QKV projection

  cvt_all_kernel<<<8192, 256, 0, stream>>>(x, wq, wk, wv, wo, xb, wqkvb, wob);

  gemm_qkv_kernel<<<dim3(32, 24), 256, 0, stream>>>(xb, wqkvb, Qb, Kb, Vtb);

  rope_kernel<<<2048, 256, 0, stream>>>(Qb, Kb, tpos);

  attn_kernel<<<512, 256, 0, stream>>>(Qb, Kb, Vtb, Aob);

  gemm_out_kernel<<<dim3(64, 8), 256, 0, stream>>>(Aob, wob, out);
}

// Round 9
// 175.408 us; speedup vs baseline: 1.4418x; 1.0397x over previous
//
#include <hip/hip_runtime.h>
#include <hip/hip_bf16.h>
#include <math.h>

#define D_MODEL 1024
#define NUM_HEADS 16
#define DK 64
#define BATCH 2
#define SEQ 2048
#define NROWS (BATCH * SEQ) /* 4096 */

typedef __bf16 bf16x8 __attribute__((ext_vector_type(8)));
typedef __bf16 bf16x4 __attribute__((ext_vector_type(4)));
typedef float f32x4 __attribute__((ext_vector_type(4)));

// async global->LDS, 16 B per lane; LDS dest = wave-uniform base + lane*16
#define GLOAD_LDS16(g, l)                                          \
  __builtin_amdgcn_global_load_lds(                                \
      (const __attribute__((address_space(1))) void*)(g),          \
      (__attribute__((address_space(3))) void*)(l), 16, 0, 0)

// LDS-only wait + compiler reorder fence (NO vmcnt drain)
#define LDS_FENCE() asm volatile("s_waitcnt lgkmcnt(0)" ::: "memory")

// ---------------- fused fp32 -> bf16 conversion ----------------------------
__global__ void cvt_all_kernel(const float* __restrict__ x,
                               const float* __restrict__ wq,
                               const float* __restrict__ wk,
                               const float* __restrict__ wv,
                               const float* __restrict__ wo,
                               __hip_bfloat16* __restrict__ xb,
                               __hip_bfloat16* __restrict__ wqkvb,
                               __hip_bfloat16* __restrict__ wob) {
  int t = blockIdx.x * 256 + threadIdx.x;  // 2,097,152 float4 units total
  const float* src;
  __hip_bfloat16* dst;
  int off;
  if (t < 1048576) {
    src = x; dst = xb; off = t;
  } else {
    int u = t - 1048576;
    int w = u >> 18;  // 262144 float4 per weight
    off = u & 262143;
    src = (w == 0) ? wq : (w == 1) ? wk : (w == 2) ? wv : wo;
    dst = (w < 3) ? (wqkvb + (size_t)w * 1048576) : wob;
  }
  float4 v = reinterpret_cast<const float4*>(src)[off];
  union { __hip_bfloat16 h[4]; uint2 u; } tmp;
  tmp.h[0] = __float2bfloat16(v.x);
  tmp.h[1] = __float2bfloat16(v.y);
  tmp.h[2] = __float2bfloat16(v.z);
  tmp.h[3] = __float2bfloat16(v.w);
  reinterpret_cast<uint2*>(dst)[off] = tmp.u;
}

// ---------------- QKV GEMM (m97 + 1-barrier dbuf) --------------------------
// C[m,n] = sum_k A[m,k] * W[n,k]; W packed (3072 rows).
// which 0/1 -> Q/K row-major WITH FUSED ROPE (applied once per element, in
// registers: pair (2p,2p+1) = adjacent even/odd lanes -> shfl_xor(1); Q also
// scaled by 0.125*log2e). which 2 -> V transposed to Vt[(b*16+h)*64+d][s].
__global__ __launch_bounds__(256)
void gemm_qkv_kernel(const __hip_bfloat16* __restrict__ A,
                     const __hip_bfloat16* __restrict__ W,
                     const int* __restrict__ tpos,
                     __hip_bfloat16* __restrict__ O0,
                     __hip_bfloat16* __restrict__ O1,
                     __hip_bfloat16* __restrict__ Vt) {
  constexpr float QS = 0.18033688011112042f;  // 0.125 * log2(e)
  __shared__ __hip_bfloat16 smem[2][2][128 * 32];  // [A/B][buf]; 32 KB
#define sAg(b) (smem[0][b])
#define sBg(b) (smem[1][b])
  const int tid = threadIdx.x;
  const int wave = tid >> 6, lane = tid & 63, quad = lane >> 4, l16 = lane & 15;
  const int wm = (wave >> 1) * 64, wn = (wave & 1) * 64;
  const int bm = blockIdx.x * 128;
  const int bnG = blockIdx.y * 128;  // row base into packed W
  const int which = blockIdx.y >> 3;
  const int ocol = bnG & 1023;
  const int srow = lane >> 2, scol = (lane & 3) * 8;

#pragma unroll
  for (int c = 0; c < 2; ++c) {
    int ch = wave + c * 4;
    GLOAD_LDS16(&A[(size_t)(bm + ch * 16 + srow) * D_MODEL + scol], &sAg(0)[ch * 512]);
    GLOAD_LDS16(&W[(size_t)(bnG + ch * 16 + srow) * D_MODEL + scol], &sBg(0)[ch * 512]);
  }

  f32x4 acc[4][4] = {};
  for (int it = 0; it < 32; ++it) {
    __syncthreads();
    if (it + 1 < 32) {
      const int k0 = (it + 1) * 32, nb = (it + 1) & 1;
#pragma unroll
      for (int c = 0; c < 2; ++c) {
        int ch = wave + c * 4;
        GLOAD_LDS16(&A[(size_t)(bm + ch * 16 + srow) * D_MODEL + k0 + scol],
                    &sAg(nb)[ch * 512]);
        GLOAD_LDS16(&W[(size_t)(bnG + ch * 16 + srow) * D_MODEL + k0 + scol],
                    &sBg(nb)[ch * 512]);
      }
    }
    const int cb = it & 1;
    bf16x8 af[4], bfb[4];
#pragma unroll
    for (int i = 0; i < 4; ++i)
      af[i] = *reinterpret_cast<bf16x8*>(&sAg(cb)[(wm + i * 16 + l16) * 32 + quad * 8]);
#pragma unroll
    for (int j = 0; j < 4; ++j)
      bfb[j] = *reinterpret_cast<bf16x8*>(&sBg(cb)[(wn + j * 16 + l16) * 32 + quad * 8]);
#pragma unroll
    for (int i = 0; i < 4; ++i)
#pragma unroll
      for (int j = 0; j < 4; ++j)
        acc[i][j] = __builtin_amdgcn_mfma_f32_16x16x32_bf16(af[i], bfb[j], acc[i][j], 0, 0, 0);
  }

  // C/D layout: col = lane&15, row = quad*4 + reg   [measured m89/m91]
  if (which < 2) {
    __hip_bfloat16* O = (which == 0) ? O0 : O1;
    const float scale = (which == 0) ? QS : 1.0f;
    const float sgn = (l16 & 1) ? 1.0f : -1.0f;  // rot = own*cs + sgn*partner*sn
    float invf[4];
#pragma unroll
    for (int j = 0; j < 4; ++j) {
      int p = ((ocol + wn + j * 16 + l16) & 63) >> 1;
      invf[j] = exp2f(-(float)p * 0.41524101186091903f);  // 10000^(-p/32)
    }
#pragma unroll
    for (int i = 0; i < 4; ++i)
#pragma unroll
      for (int r = 0; r < 4; ++r) {
        int row = bm + wm + i * 16 + quad * 4 + r;
        float pos = (float)tpos[row];
#pragma unroll
        for (int j = 0; j < 4; ++j) {
          float v = acc[i][j][r];
          float partner = __shfl_xor(v, 1);
          float sn, cs;
          __sincosf(pos * invf[j], &sn, &cs);
          float rot = (v * cs + sgn * partner * sn) * scale;
          int col = ocol + wn + j * 16 + l16;
          O[(size_t)row * D_MODEL + col] = __float2bfloat16(rot);
        }
      }
  } else {
    // V-transpose epilogue: 128x128 tile -> LDS (swizzled) -> Vt coalesced.
    __syncthreads();  // all waves done with sA/sB MFMA reads
    __hip_bfloat16* tr = &smem[0][0][0];  // 128 x 128 bf16 = 32 KB
#pragma unroll
    for (int i = 0; i < 4; ++i)
#pragma unroll
      for (int j = 0; j < 4; ++j) {
        int c = wn + j * 16 + l16;
        int r = wm + i * 16 + quad * 4;
        bf16x4 pk;
#pragma unroll
        for (int rr = 0; rr < 4; ++rr) pk[rr] = (__bf16)acc[i][j][rr];
        int g = (r >> 3) ^ (c & 15);
        *reinterpret_cast<bf16x4*>(&tr[c * 128 + g * 8 + (r & 7)]) = pk;
      }
    __syncthreads();
    int c = tid >> 1;
    int vcol = ocol + c;  // global v-dim 0..1023
    int hh = vcol >> 6, dd = vcol & 63;
    int bb = bm >> 11, s0 = (bm & 2047) + (tid & 1) * 64;
    __hip_bfloat16* dst = Vt + ((size_t)(bb * 16 + hh) * 64 + dd) * 2048 + s0;
    int gbase = (tid & 1) * 8;
#pragma unroll
    for (int k = 0; k < 8; ++k) {
      int g = (gbase + k) ^ (c & 15);
      *reinterpret_cast<bf16x8*>(&dst[k * 8]) =
          *reinterpret_cast<bf16x8*>(&tr[c * 128 + g * 8]);
    }
  }
#undef sAg
#undef sBg
}

// ---------------- out-proj GEMM, 64x64 tile (1024 blocks -> 4/CU) ----------
__global__ __launch_bounds__(256)
void gemm_out_kernel(const __hip_bfloat16* __restrict__ A,
                     const __hip_bfloat16* __restrict__ W,
                     float* __restrict__ O) {
  __shared__ __hip_bfloat16 sA[2][64 * 32];
  __shared__ __hip_bfloat16 sB[2][64 * 32];
  const int tid = threadIdx.x;
  const int wave = tid >> 6, lane = tid & 63, quad = lane >> 4, l16 = lane & 15;
  const int mh = (wave >> 1) * 32, nh = (wave & 1) * 32;
  const int bm = blockIdx.x * 64, bn = blockIdx.y * 64;
  const int srow = lane >> 2, scol = (lane & 3) * 8;

  GLOAD_LDS16(&A[(size_t)(bm + wave * 16 + srow) * D_MODEL + scol], &sA[0][wave * 512]);
  GLOAD_LDS16(&W[(size_t)(bn + wave * 16 + srow) * D_MODEL + scol], &sB[0][wave * 512]);

  f32x4 acc[2][2] = {};
  for (int it = 0; it < 32; ++it) {
    __syncthreads();
    if (it + 1 < 32) {
      const int k0 = (it + 1) * 32, nb = (it + 1) & 1;
      GLOAD_LDS16(&A[(size_t)(bm + wave * 16 + srow) * D_MODEL + k0 + scol],
                  &sA[nb][wave * 512]);
      GLOAD_LDS16(&W[(size_t)(bn + wave * 16 + srow) * D_MODEL + k0 + scol],
                  &sB[nb][wave * 512]);
    }
    const int cb = it & 1;
    bf16x8 af[2], bfb[2];
#pragma unroll
    for (int i = 0; i < 2; ++i)
      af[i] = *reinterpret_cast<bf16x8*>(&sA[cb][(mh + i * 16 + l16) * 32 + quad * 8]);
#pragma unroll
    for (int j = 0; j < 2; ++j)
      bfb[j] = *reinterpret_cast<bf16x8*>(&sB[cb][(nh + j * 16 + l16) * 32 + quad * 8]);
#pragma unroll
    for (int i = 0; i < 2; ++i)
#pragma unroll
      for (int j = 0; j < 2; ++j)
        acc[i][j] = __builtin_amdgcn_mfma_f32_16x16x32_bf16(af[i], bfb[j], acc[i][j], 0, 0, 0);
  }

#pragma unroll
  for (int i = 0; i < 2; ++i)
#pragma unroll
    for (int j = 0; j < 2; ++j)
#pragma unroll
      for (int r = 0; r < 4; ++r) {
        int row = bm + mh + i * 16 + quad * 4 + r;
        int col = bn + nh + j * 16 + l16;
        O[(size_t)row * D_MODEL + col] = acc[i][j][r];
      }
}

// ---------------- Flash attention (causal), balanced + swizzled ------------
// 256 thd = 4 waves; 512 balanced blocks (pair qlo=pi with qhi=15-pi).
// S^T orientation; K and V^T staged into XOR-granule-swizzled LDS
// (stride 64, granule g at g^(row&7)): conflict-free reads AND writes.
// V from pre-transposed Vt. Dbuf + register prefetch, one barrier per
// kv-tile, no max-subtraction, XOR-swizzled sPt. RoPE pre-applied in the
// QKV GEMM epilogue (once per element — recompute here was 2x regression).
__global__ __launch_bounds__(256)
void attn_kernel(const __hip_bfloat16* __restrict__ Q,
                 const __hip_bfloat16* __restrict__ K,
                 const __hip_bfloat16* __restrict__ Vt,
                 __hip_bfloat16* __restrict__ Ao) {
  __shared__ __hip_bfloat16 sK[2][64 * 64];
  __shared__ __hip_bfloat16 sVt[2][64 * 64];  // [d][kv], swizzled
  __shared__ __hip_bfloat16 sPt[4][16 * 64];  // per-wave, swizzled
  const int tid = threadIdx.x;
  const int wave = tid >> 6, lane = tid & 63, quad = lane >> 4, l16 = lane & 15;
  const int idx = blockIdx.x;            // 512 blocks, all equal work
  const int bh = idx & 31;
  const int half = (idx >> 5) & 1;
  const int pi = idx >> 6;               // 0..7
  const int qlo = pi, qhi = 15 - pi;
  const int h = bh & 15, b = bh >> 4;
  const int ho = h * DK;
  const size_t rowbase = (size_t)b * SEQ;
  const int jL = half * 4 + wave, jU = 7 - jL;
  const int sbs[2] = {qlo * 128 + jL * 16, qhi * 128 + jU * 16};  // sbs[1]>sbs[0]
  const int nt = ((qhi * 128 + (7 - half * 4) * 16 + 15) >> 6) + 1;
  const __hip_bfloat16* Kbase = K + rowbase * D_MODEL + ho;
  const __hip_bfloat16* Vtbase = Vt + (size_t)(b * 16 + h) * 64 * 2048;

  // Q fragments (B-operand; lane l16 = q-row; rope+scale pre-applied)
  bf16x8 aq[2][2];
#pragma unroll
  for (int s = 0; s < 2; ++s)
#pragma unroll
    for (int kk = 0; kk < 2; ++kk)
      aq[s][kk] = *reinterpret_cast<const bf16x8*>(
          &Q[(rowbase + sbs[s] + l16) * D_MODEL + ho + kk * 32 + quad * 8]);

  f32x4 o_acc[2][4] = {};
  float l_run[2] = {0.f, 0.f};

  // staging maps: row = tid>>2 (64 rows), granules ga,ga+1 (= (tid&3)*2)
  const int srow = tid >> 2, sc = (tid & 3) * 16;
  const int ga = (tid & 3) * 2;
  const int sga = (ga ^ (srow & 7)) * 8, sgb = ((ga + 1) ^ (srow & 7)) * 8;

  // prologue: stage tile 0 into buffer 0
  {
    bf16x8 k0 = *reinterpret_cast<const bf16x8*>(&Kbase[(size_t)srow * D_MODEL + sc]);
    bf16x8 k1 = *reinterpret_cast<const bf16x8*>(&Kbase[(size_t)srow * D_MODEL + sc + 8]);
    bf16x8 v0 = *reinterpret_cast<const bf16x8*>(&Vtbase[(size_t)srow * 2048 + sc]);
    bf16x8 v1 = *reinterpret_cast<const bf16x8*>(&Vtbase[(size_t)srow * 2048 + sc + 8]);
    *reinterpret_cast<bf16x8*>(&sK[0][srow * 64 + sga]) = k0;
    *reinterpret_cast<bf16x8*>(&sK[0][srow * 64 + sgb]) = k1;
    *reinterpret_cast<bf16x8*>(&sVt[0][srow * 64 + sga]) = v0;
    *reinterpret_cast<bf16x8*>(&sVt[0][srow * 64 + sgb]) = v1;
  }

  for (int t = 0; t < nt; ++t) {
    __syncthreads();  // staging for tile t visible
    const int buf = t & 1;
    const bool hn = (t + 1) < nt;
    bf16x8 kn0, kn1, vn0, vn1;
    if (hn) {  // register prefetch of next tile (latency overlapped)
      const int kvn = (t + 1) * 64;
      kn0 = *reinterpret_cast<const bf16x8*>(
          &Kbase[(size_t)(kvn + srow) * D_MODEL + sc]);
      kn1 = *reinterpret_cast<const bf16x8*>(
          &Kbase[(size_t)(kvn + srow) * D_MODEL + sc + 8]);
      vn0 = *reinterpret_cast<const bf16x8*>(
          &Vtbase[(size_t)srow * 2048 + kvn + sc]);
      vn1 = *reinterpret_cast<const bf16x8*>(
          &Vtbase[(size_t)srow * 2048 + kvn + sc + 8]);
    }

    const int kv0 = t * 64;
    if (kv0 <= sbs[1] + 15) {
      // q-independent fragments: load once, reuse for both subtiles
      bf16x8 ak[2][4], bv[2][4];
#pragma unroll
      for (int kk = 0; kk < 2; ++kk)
#pragma unroll
        for (int j = 0; j < 4; ++j) {
          int go = ((4 * kk + quad) ^ (l16 & 7)) * 8;
          ak[kk][j] = *reinterpret_cast<bf16x8*>(&sK[buf][(j * 16 + l16) * 64 + go]);
          bv[kk][j] = *reinterpret_cast<bf16x8*>(&sVt[buf][(j * 16 + l16) * 64 + go]);
        }

#pragma unroll
      for (int s = 0; s < 2; ++s) {
        const int sb = sbs[s];
        if (kv0 > sb + 15) continue;
        // S^T = K Q^T : lane holds S[q=sb+l16][kv0 + 16j + 4quad + r]
        f32x4 sv[4] = {};
#pragma unroll
        for (int kk = 0; kk < 2; ++kk)
#pragma unroll
          for (int j = 0; j < 4; ++j)
            sv[j] = __builtin_amdgcn_mfma_f32_16x16x32_bf16(ak[kk][j], aq[s][kk],
                                                            sv[j], 0, 0, 0);
        // Causal mask (diagonal-crossing tiles only)
        if (kv0 + 63 > sb) {
#pragma unroll
          for (int j = 0; j < 4; ++j)
#pragma unroll
            for (int r = 0; r < 4; ++r)
              if (kv0 + j * 16 + quad * 4 + r > sb + l16) sv[j][r] = -INFINITY;
        }
        // exp2; in-lane row-sum; write P rows (q=l16) XOR-swizzled, b64
        float ls = 0.f;
#pragma unroll
        for (int j = 0; j < 4; ++j) {
          bf16x4 pk;
#pragma unroll
          for (int r = 0; r < 4; ++r) {
            float p = __builtin_amdgcn_exp2f(sv[j][r]);
            ls += p;
            pk[r] = (__bf16)p;
          }
          int wgr = (2 * j + (quad >> 1)) ^ (l16 & 7);  // 4-dword granule
          *reinterpret_cast<bf16x4*>(
              &sPt[wave][l16 * 64 + wgr * 8 + (quad & 1) * 4]) = pk;
        }
        l_run[s] += ls;
        LDS_FENCE();  // order sPt write->read (same wave); vmcnt untouched
        // O += P V
#pragma unroll
        for (int kk = 0; kk < 2; ++kk) {
          int rgr = (4 * kk + quad) ^ (l16 & 7);
          bf16x8 ap = *reinterpret_cast<bf16x8*>(&sPt[wave][l16 * 64 + rgr * 8]);
#pragma unroll
          for (int jd = 0; jd < 4; ++jd)
            o_acc[s][jd] = __builtin_amdgcn_mfma_f32_16x16x32_bf16(
                ap, bv[kk][jd], o_acc[s][jd], 0, 0, 0);
        }
      }
    }

    if (hn) {  // commit prefetched tile into the other buffer (swizzled)
      const int nb = buf ^ 1;
      *reinterpret_cast<bf16x8*>(&sK[nb][srow * 64 + sga]) = kn0;
      *reinterpret_cast<bf16x8*>(&sK[nb][srow * 64 + sgb]) = kn1;
      *reinterpret_cast<bf16x8*>(&sVt[nb][srow * 64 + sga]) = vn0;
      *reinterpret_cast<bf16x8*>(&sVt[nb][srow * 64 + sgb]) = vn1;
    }
  }

  // epilogue: per-subtile l reduction (across quads) + normalize + store
#pragma unroll
  for (int s = 0; s < 2; ++s) {
    float l = l_run[s];
    l += __shfl_xor(l, 16);
    l += __shfl_xor(l, 32);  // every lane: total for q-row (lane&15)
    __hip_bfloat16* Aobase = Ao + (rowbase + sbs[s]) * D_MODEL + ho;
#pragma unroll
    for (int r = 0; r < 4; ++r) {
      float linv = 1.0f / __shfl(l, quad * 4 + r);  // lane n<16 holds row n
#pragma unroll
      for (int jd = 0; jd < 4; ++jd)
        Aobase[(size_t)(quad * 4 + r) * D_MODEL + jd * 16 + l16] =
            __float2bfloat16(o_acc[s][jd][r] * linv);
    }
  }
}

// ---------------- launch ----------------
extern "C" void kernel_launch(void* const* d_in, const int* in_sizes, int n_in,
                              void* d_out, int out_size, void* d_ws, size_t ws_size,
                              hipStream_t stream) {
  const float* x = (const float*)d_in[0];
  const float* wq = (const float*)d_in[1];
  const float* wk = (const float*)d_in[2];
  const float* wv = (const float*)d_in[3];
  const float* wo = (const float*)d_in[4];
  const int* tpos = (const int*)d_in[5];
  float* out = (float*)d_out;
  char* ws = (char*)d_ws;

  __hip_bfloat16* xb    = (__hip_bfloat16*)(ws);                      // 8 MiB
  __hip_bfloat16* wqkvb = (__hip_bfloat16*)(ws + (size_t)(8)  * 1048576); // 6
  __hip_bfloat16* wob   = (__hip_bfloat16*)(ws + (size_t)(14) * 1048576); // 2
  __hip_bfloat16* Qb    = (__hip_bfloat16*)(ws + (size_t)(16) * 1048576);
  __hip_bfloat16* Kb    = (__hip_bfloat16*)(ws + (size_t)(24) * 1048576);
  __hip_bfloat16* Vtb   = (__hip_bfloat16*)(ws + (size_t)(32) * 1048576);
  __hip_bfloat16* Aob   = xb;  // x dead after QKV projection

  cvt_all_kernel<<<8192, 256, 0, stream>>>(x, wq, wk, wv, wo, xb, wqkvb, wob);

  gemm_qkv_kernel<<<dim3(32, 24), 256, 0, stream>>>(xb, wqkvb, tpos, Qb, Kb, Vtb);

  attn_kernel<<<512, 256, 0, stream>>>(Qb, Kb, Vtb, Aob);

  gemm_out_kernel<<<dim3(64, 16), 256, 0, stream>>>(Aob, wob, out);
}